// Round 1
// baseline (159.045 us; speedup 1.0000x reference)
//
#include <hip/hip_runtime.h>
#include <math.h>

#define KSIZE 11
#define PAD 5

struct GaussW { float w[KSIZE]; };

// ---------------------------------------------------------------------------
// Pass along W (contiguous axis). Each thread produces one aligned float4 of
// output. Input window w0-5 .. w0+8 (14 floats) is covered by 5 aligned
// float4 loads at float4-offsets {-2,-1,0,+1,+2}; out-of-row loads zeroed.
// ---------------------------------------------------------------------------
template <int W>
__global__ __launch_bounds__(256) void blur_w_pass(const float4* __restrict__ src,
                                                   float4* __restrict__ dst,
                                                   GaussW g, int n4) {
    constexpr int W4 = W / 4;
    int i = blockIdx.x * blockDim.x + threadIdx.x;
    if (i >= n4) return;
    int w4 = i % W4;

    float win[20];
#pragma unroll
    for (int j = 0; j < 5; ++j) {
        int q = w4 + j - 2;  // float4 column within the row
        float4 v = make_float4(0.f, 0.f, 0.f, 0.f);
        if (q >= 0 && q < W4) v = src[i + (j - 2)];
        win[4 * j + 0] = v.x;
        win[4 * j + 1] = v.y;
        win[4 * j + 2] = v.z;
        win[4 * j + 3] = v.w;
    }
    // win[k] holds input element (w0 - 8 + k). Output w0+e needs win[8+e-5+t].
    float4 acc = make_float4(0.f, 0.f, 0.f, 0.f);
#pragma unroll
    for (int t = 0; t < KSIZE; ++t) {
        float wt = g.w[t];
        acc.x += wt * win[3 + t];
        acc.y += wt * win[4 + t];
        acc.z += wt * win[5 + t];
        acc.w += wt * win[6 + t];
    }
    dst[i] = acc;
}

// ---------------------------------------------------------------------------
// Pass along a strided axis (H or D). STR4 = axis stride in float4 units,
// LEN = axis length. Each thread: one float4 output, 11 strided float4 loads
// (coalesced across lanes; neighbor-row reuse via L1/L2).
// ---------------------------------------------------------------------------
template <int STR4, int LEN>
__global__ __launch_bounds__(256) void blur_axis_pass(const float4* __restrict__ src,
                                                      float4* __restrict__ dst,
                                                      GaussW g, int n4) {
    int i = blockIdx.x * blockDim.x + threadIdx.x;
    if (i >= n4) return;
    int c = (i / STR4) % LEN;

    float4 acc = make_float4(0.f, 0.f, 0.f, 0.f);
#pragma unroll
    for (int t = 0; t < KSIZE; ++t) {
        int cc = c + t - PAD;
        if (cc >= 0 && cc < LEN) {
            float4 v = src[i + (t - PAD) * STR4];
            float wt = g.w[t];
            acc.x += wt * v.x;
            acc.y += wt * v.y;
            acc.z += wt * v.z;
            acc.w += wt * v.w;
        }
    }
    dst[i] = acc;
}

// ---------------------------------------------------------------------------
// Dense fallback (only if ws is too small for the ping-pong buffer).
// ---------------------------------------------------------------------------
__global__ void blur_dense_fallback(const float* __restrict__ src,
                                    float* __restrict__ dst,
                                    GaussW g, int B, int D, int H, int W) {
    long n = (long)B * D * H * W;
    long i = (long)blockIdx.x * blockDim.x + threadIdx.x;
    if (i >= n) return;
    int w = (int)(i % W);
    long r = i / W;
    int h = (int)(r % H);
    r /= H;
    int d = (int)(r % D);
    int b = (int)(r / D);

    float acc = 0.f;
    for (int td = 0; td < KSIZE; ++td) {
        int dd = d + td - PAD;
        if (dd < 0 || dd >= D) continue;
        for (int th = 0; th < KSIZE; ++th) {
            int hh = h + th - PAD;
            if (hh < 0 || hh >= H) continue;
            float wdh = g.w[td] * g.w[th];
            const float* row = src + (((long)b * D + dd) * H + hh) * W;
            for (int tw = 0; tw < KSIZE; ++tw) {
                int ww = w + tw - PAD;
                if (ww < 0 || ww >= W) continue;
                acc += wdh * g.w[tw] * row[ww];
            }
        }
    }
    dst[i] = acc;
}

extern "C" void kernel_launch(void* const* d_in, const int* in_sizes, int n_in,
                              void* d_out, int out_size, void* d_ws, size_t ws_size,
                              hipStream_t stream) {
    const float* x = (const float*)d_in[0];
    float* out = (float*)d_out;
    float* ws = (float*)d_ws;

    const int B = 4, D = 160, H = 192, W = 192;
    const long n = (long)B * D * H * W;       // 23,592,960
    const int n4 = (int)(n / 4);              // 5,898,240

    // Gaussian weights, sigma = 1.5, ksize = 11, normalized.
    GaussW g;
    {
        double tmp[KSIZE], s = 0.0;
        for (int i = 0; i < KSIZE; ++i) {
            double dd = (double)(i - PAD);
            tmp[i] = exp(-(dd * dd) / (2.0 * 1.5 * 1.5));
            s += tmp[i];
        }
        for (int i = 0; i < KSIZE; ++i) g.w[i] = (float)(tmp[i] / s);
    }

    const int block = 256;
    const int grid = (n4 + block - 1) / block;

    if (ws_size >= (size_t)n * sizeof(float)) {
        // W pass: x -> out
        blur_w_pass<192><<<grid, block, 0, stream>>>((const float4*)x, (float4*)out, g, n4);
        // H pass: out -> ws   (stride in float4 units = W/4 = 48)
        blur_axis_pass<48, 192><<<grid, block, 0, stream>>>((const float4*)out, (float4*)ws, g, n4);
        // D pass: ws -> out   (stride = H*W/4 = 9216)
        blur_axis_pass<9216, 160><<<grid, block, 0, stream>>>((const float4*)ws, (float4*)out, g, n4);
    } else {
        long gridN = (n + block - 1) / block;
        blur_dense_fallback<<<(int)gridN, block, 0, stream>>>(x, out, g, B, D, H, W);
    }
}

// Round 2
// 109.700 us; speedup vs baseline: 1.4498x; 1.4498x over previous
//
#include <hip/hip_runtime.h>
#include <math.h>

#define KSIZE 11
#define PAD 5

struct GaussW { float w[KSIZE]; };

// ---------------------------------------------------------------------------
// Pass along W (contiguous axis). Each thread produces one aligned float4 of
// output from 5 aligned float4 loads (neighbor overlap served by L1/L2).
// Near-roofline already (~31 us, ~6 TB/s) — unchanged from R0.
// ---------------------------------------------------------------------------
template <int W>
__global__ __launch_bounds__(256) void blur_w_pass(const float4* __restrict__ src,
                                                   float4* __restrict__ dst,
                                                   GaussW g, int n4) {
    constexpr int W4 = W / 4;
    int i = blockIdx.x * blockDim.x + threadIdx.x;
    if (i >= n4) return;
    int w4 = i % W4;

    float win[20];
#pragma unroll
    for (int j = 0; j < 5; ++j) {
        int q = w4 + j - 2;
        float4 v = make_float4(0.f, 0.f, 0.f, 0.f);
        if (q >= 0 && q < W4) v = src[i + (j - 2)];
        win[4 * j + 0] = v.x;
        win[4 * j + 1] = v.y;
        win[4 * j + 2] = v.z;
        win[4 * j + 3] = v.w;
    }
    float4 acc = make_float4(0.f, 0.f, 0.f, 0.f);
#pragma unroll
    for (int t = 0; t < KSIZE; ++t) {
        float wt = g.w[t];
        acc.x += wt * win[3 + t];
        acc.y += wt * win[4 + t];
        acc.z += wt * win[5 + t];
        acc.w += wt * win[6 + t];
    }
    dst[i] = acc;
}

// ---------------------------------------------------------------------------
// Sliding-window pass along a strided axis (H or D).
// Each thread owns CH consecutive outputs of one column (fixed b, inner
// coords), keeps the last 11 inputs in a register ring (static indices after
// full unroll), loads each input exactly once. STR4 = axis stride in float4
// units, LEN = axis length, CH divides LEN.
// ncol must be a multiple of blockDim (256) so chunk is block-uniform.
// ---------------------------------------------------------------------------
template <int STR4, int LEN, int CH>
__global__ __launch_bounds__(256) void blur_axis_slide(const float4* __restrict__ src,
                                                       float4* __restrict__ dst,
                                                       GaussW g, int ncol) {
    int tid = blockIdx.x * blockDim.x + threadIdx.x;
    int col = tid % ncol;
    int chunk = tid / ncol;
    int c0 = chunk * CH;
    int inner = col % STR4;
    int outer = col / STR4;
    int base = outer * (LEN * STR4) + inner;   // < 6M, fits int

    float4 ring[KSIZE];
    // Preload inputs at positions c0-PAD .. c0+PAD-1 (10 entries).
#pragma unroll
    for (int j = 0; j < KSIZE - 1; ++j) {
        int cc = c0 - PAD + j;
        float4 v = make_float4(0.f, 0.f, 0.f, 0.f);
        if (cc >= 0 && cc < LEN) v = src[base + cc * STR4];
        ring[j] = v;
    }
    // ring slot for input position m (= c0-PAD+idx) is idx % KSIZE.
#pragma unroll
    for (int k = 0; k < CH; ++k) {
        int cc = c0 + k + PAD;                 // always >= 0
        float4 v = make_float4(0.f, 0.f, 0.f, 0.f);
        if (cc < LEN) v = src[base + cc * STR4];
        ring[(KSIZE - 1 + k) % KSIZE] = v;

        float4 acc = make_float4(0.f, 0.f, 0.f, 0.f);
#pragma unroll
        for (int t = 0; t < KSIZE; ++t) {
            float4 u = ring[(k + t) % KSIZE];  // static index after unroll
            float wt = g.w[t];
            acc.x += wt * u.x;
            acc.y += wt * u.y;
            acc.z += wt * u.z;
            acc.w += wt * u.w;
        }
        dst[base + (c0 + k) * STR4] = acc;
    }
}

// ---------------------------------------------------------------------------
// Dense fallback (only if ws is too small for the ping-pong buffer).
// ---------------------------------------------------------------------------
__global__ void blur_dense_fallback(const float* __restrict__ src,
                                    float* __restrict__ dst,
                                    GaussW g, int B, int D, int H, int W) {
    long n = (long)B * D * H * W;
    long i = (long)blockIdx.x * blockDim.x + threadIdx.x;
    if (i >= n) return;
    int w = (int)(i % W);
    long r = i / W;
    int h = (int)(r % H);
    r /= H;
    int d = (int)(r % D);
    int b = (int)(r / D);

    float acc = 0.f;
    for (int td = 0; td < KSIZE; ++td) {
        int dd = d + td - PAD;
        if (dd < 0 || dd >= D) continue;
        for (int th = 0; th < KSIZE; ++th) {
            int hh = h + th - PAD;
            if (hh < 0 || hh >= H) continue;
            float wdh = g.w[td] * g.w[th];
            const float* row = src + (((long)b * D + dd) * H + hh) * W;
            for (int tw = 0; tw < KSIZE; ++tw) {
                int ww = w + tw - PAD;
                if (ww < 0 || ww >= W) continue;
                acc += wdh * g.w[tw] * row[ww];
            }
        }
    }
    dst[i] = acc;
}

extern "C" void kernel_launch(void* const* d_in, const int* in_sizes, int n_in,
                              void* d_out, int out_size, void* d_ws, size_t ws_size,
                              hipStream_t stream) {
    const float* x = (const float*)d_in[0];
    float* out = (float*)d_out;
    float* ws = (float*)d_ws;

    const int B = 4, D = 160, H = 192, W = 192;
    const long n = (long)B * D * H * W;       // 23,592,960
    const int n4 = (int)(n / 4);              // 5,898,240
    const int W4 = W / 4;                     // 48

    // Gaussian weights, sigma = 1.5, ksize = 11, normalized.
    GaussW g;
    {
        double tmp[KSIZE], s = 0.0;
        for (int i = 0; i < KSIZE; ++i) {
            double dd = (double)(i - PAD);
            tmp[i] = exp(-(dd * dd) / (2.0 * 1.5 * 1.5));
            s += tmp[i];
        }
        for (int i = 0; i < KSIZE; ++i) g.w[i] = (float)(tmp[i] / s);
    }

    const int block = 256;

    if (ws_size >= (size_t)n * sizeof(float)) {
        // W pass: x -> out
        {
            int grid = (n4 + block - 1) / block;
            blur_w_pass<192><<<grid, block, 0, stream>>>(
                (const float4*)x, (float4*)out, g, n4);
        }
        // H pass: out -> ws. stride = W4 = 48, LEN = 192, CH = 32 (6 chunks).
        {
            const int ncol = B * D * W4;              // 30720 (mult of 256)
            const int threads = ncol * (H / 32);      // 184320
            blur_axis_slide<48, 192, 32><<<threads / block, block, 0, stream>>>(
                (const float4*)out, (float4*)ws, g, ncol);
        }
        // D pass: ws -> out. stride = H*W4 = 9216, LEN = 160, CH = 32 (5 chunks).
        {
            const int ncol = B * H * W4;              // 36864 (mult of 256)
            const int threads = ncol * (D / 32);      // 184320
            blur_axis_slide<9216, 160, 32><<<threads / block, block, 0, stream>>>(
                (const float4*)ws, (float4*)out, g, ncol);
        }
    } else {
        long gridN = (n + block - 1) / block;
        blur_dense_fallback<<<(int)gridN, block, 0, stream>>>(x, out, g, B, D, H, W);
    }
}

// Round 3
// 89.057 us; speedup vs baseline: 1.7859x; 1.2318x over previous
//
#include <hip/hip_runtime.h>
#include <math.h>

#define KSIZE 11
#define PAD 5

struct GaussW { float w[KSIZE]; };

#define B_    4
#define D_    160
#define H_    192
#define W_    192
#define W4_   48          // W in float4 units
#define TH    32          // tile rows (h)
#define DSEG  32          // D-segment per block
#define NH    (H_ / TH)   // 6
#define NWT   (W_ / 32)   // 6
#define NDS   (D_ / DSEG) // 5
#define NBLK  (B_ * NH * NWT * NDS)        // 720
#define NSTEP (DSEG + KSIZE - 1)           // 42

#define IN_STR 52   // LDS row stride (floats), 48 used + pad, 16B-aligned
#define WT_STR 36   // LDS row stride (floats), 32 used + pad, 16B-aligned

__global__ __launch_bounds__(256) void blur3d_fused(const float4* __restrict__ src,
                                                    float4* __restrict__ dst,
                                                    GaussW g) {
    __shared__ float lds_in[42 * IN_STR];   // raw input plane tile (w-halo + h-halo)
    __shared__ float lds_wt[42 * WT_STR];   // W-filtered plane tile (h-halo kept)

    // Chunked XCD swizzle: 720 blocks % 8 == 0 -> chunks of 90; consecutive
    // logical ids (d-neighbor segments, then w-neighbors) stay on one XCD.
    int bid = blockIdx.x;
    int L = (bid & 7) * (NBLK / 8) + (bid >> 3);
    int ds = L % NDS; L /= NDS;
    int wx = L % NWT; L /= NWT;
    int hy = L % NH;
    int b  = L / NH;

    const int h0  = hy * TH;
    const int w0q = wx * 8;          // tile origin in float4 units
    const int d0  = ds * DSEG;

    const int tid = threadIdx.x;
    const int tx  = tid & 7;         // output col4 0..7
    const int ty  = tid >> 3;        // output row 0..31

    // Stage-load item decode: 42 rows x 12 float4 = 504 items, 2 per thread.
    const int i0r = tid / 12,          i0j = tid % 12;
    const int i1r = (tid + 256) / 12,  i1j = (tid + 256) % 12;

    const int batchBase = b * (D_ * H_ * W4_);   // float4 index, < 2^31

    float4 ring[KSIZE];
#pragma unroll
    for (int t = 0; t < KSIZE; ++t) ring[t] = make_float4(0.f, 0.f, 0.f, 0.f);

    float4 pf0, pf1;
    auto issue_loads = [&](int din, float4& v0, float4& v1) {
        v0 = make_float4(0.f, 0.f, 0.f, 0.f);
        v1 = make_float4(0.f, 0.f, 0.f, 0.f);
        if (din >= 0 && din < D_) {
            const float4* plane = src + batchBase + din * (H_ * W4_);
            int h = h0 - PAD + i0r;
            int q = w0q - 2 + i0j;
            if (h >= 0 && h < H_ && q >= 0 && q < W4_) v0 = plane[h * W4_ + q];
            int h1 = h0 - PAD + i1r;
            int q1 = w0q - 2 + i1j;
            if (tid < 248 && h1 >= 0 && h1 < H_ && q1 >= 0 && q1 < W4_)
                v1 = plane[h1 * W4_ + q1];
        }
    };

    issue_loads(d0 - PAD, pf0, pf1);

    for (int k = 0; k < NSTEP; ++k) {
        const int din = d0 - PAD + k;

        __syncthreads();   // prev W-conv reads of lds_in done; prev H reads of lds_wt done
        *(float4*)&lds_in[i0r * IN_STR + i0j * 4] = pf0;
        if (tid < 248) *(float4*)&lds_in[i1r * IN_STR + i1j * 4] = pf1;
        __syncthreads();

        // Prefetch next plane (completes under the conv phases below).
        issue_loads(din + 1, pf0, pf1);

        // ---- W-conv: 336 items (42 rows x 8 col4), items tid and tid+256 ----
        {
            const int r = tid >> 3, c4 = tid & 7;
            float win[20];
            const float* row = &lds_in[r * IN_STR + c4 * 4];
#pragma unroll
            for (int u = 0; u < 5; ++u) {
                float4 v = *(const float4*)&row[u * 4];
                win[4 * u + 0] = v.x; win[4 * u + 1] = v.y;
                win[4 * u + 2] = v.z; win[4 * u + 3] = v.w;
            }
            float4 a = make_float4(0.f, 0.f, 0.f, 0.f);
#pragma unroll
            for (int t = 0; t < KSIZE; ++t) {
                float wt = g.w[t];
                a.x += wt * win[3 + t]; a.y += wt * win[4 + t];
                a.z += wt * win[5 + t]; a.w += wt * win[6 + t];
            }
            *(float4*)&lds_wt[r * WT_STR + c4 * 4] = a;

            if (tid < 80) {  // second item: rows 32..41
                const int r2 = r + 32;
                const float* row2 = &lds_in[r2 * IN_STR + c4 * 4];
#pragma unroll
                for (int u = 0; u < 5; ++u) {
                    float4 v = *(const float4*)&row2[u * 4];
                    win[4 * u + 0] = v.x; win[4 * u + 1] = v.y;
                    win[4 * u + 2] = v.z; win[4 * u + 3] = v.w;
                }
                float4 a2 = make_float4(0.f, 0.f, 0.f, 0.f);
#pragma unroll
                for (int t = 0; t < KSIZE; ++t) {
                    float wt = g.w[t];
                    a2.x += wt * win[3 + t]; a2.y += wt * win[4 + t];
                    a2.z += wt * win[5 + t]; a2.w += wt * win[6 + t];
                }
                *(float4*)&lds_wt[r2 * WT_STR + c4 * 4] = a2;
            }
        }
        __syncthreads();

        // ---- H-conv: one float4 per thread ----
        float4 wh = make_float4(0.f, 0.f, 0.f, 0.f);
#pragma unroll
        for (int t = 0; t < KSIZE; ++t) {
            float4 v = *(const float4*)&lds_wt[(ty + t) * WT_STR + tx * 4];
            float wt = g.w[t];
            wh.x += wt * v.x; wh.y += wt * v.y;
            wh.z += wt * v.z; wh.w += wt * v.w;
        }

        // ---- ring shift (static indices) + push ----
#pragma unroll
        for (int t = 0; t < KSIZE - 1; ++t) ring[t] = ring[t + 1];
        ring[KSIZE - 1] = wh;

        // ---- D-conv + emit ----
        if (k >= KSIZE - 1) {
            const int dout = din - PAD;   // in [d0, d0+DSEG)
            float4 o = make_float4(0.f, 0.f, 0.f, 0.f);
#pragma unroll
            for (int t = 0; t < KSIZE; ++t) {
                float wt = g.w[t];
                o.x += wt * ring[t].x; o.y += wt * ring[t].y;
                o.z += wt * ring[t].z; o.w += wt * ring[t].w;
            }
            dst[batchBase + dout * (H_ * W4_) + (h0 + ty) * W4_ + w0q + tx] = o;
        }
    }
}

extern "C" void kernel_launch(void* const* d_in, const int* in_sizes, int n_in,
                              void* d_out, int out_size, void* d_ws, size_t ws_size,
                              hipStream_t stream) {
    const float* x = (const float*)d_in[0];
    float* out = (float*)d_out;
    (void)d_ws; (void)ws_size; (void)in_sizes; (void)n_in; (void)out_size;

    // Gaussian weights, sigma = 1.5, ksize = 11, normalized.
    GaussW g;
    {
        double tmp[KSIZE], s = 0.0;
        for (int i = 0; i < KSIZE; ++i) {
            double dd = (double)(i - PAD);
            tmp[i] = exp(-(dd * dd) / (2.0 * 1.5 * 1.5));
            s += tmp[i];
        }
        for (int i = 0; i < KSIZE; ++i) g.w[i] = (float)(tmp[i] / s);
    }

    blur3d_fused<<<NBLK, 256, 0, stream>>>((const float4*)x, (float4*)out, g);
}